// Round 19
// baseline (461.819 us; speedup 1.0000x reference)
//
#include <hip/hip_runtime.h>
#include <cstdint>
#include <climits>

#define N 8192
#define D 64
#define H 128
#define O 64
#define KNB 16
#define NE (N*KNB)        // 131072
#define ETOT (NE + N)     // 139264
#define OUT0 (N*D)        // 524288
#define NSPL 32           // j-splits (chunks)
#define JSPAN 256         // j's per chunk (N/NSPL)
#define JTILE 128         // j-rows staged in LDS per tile (32 KB)
#define TCH 8             // stored top-T per chunk (certificate depth)

__device__ __forceinline__ float bf2f(unsigned short u){
    union { unsigned int u; float f; } v; v.u = ((unsigned int)u) << 16; return v.f;
}
__device__ __forceinline__ unsigned short f2bf(float f){
    union { float f; unsigned int u; } v; v.f = f;
    unsigned int r = v.u + 0x7FFFu + ((v.u >> 16) & 1u);   // RNE
    return (unsigned short)(r >> 16);
}

#define PIN4(v) asm volatile("" : "+v"((v).x), "+v"((v).y), "+v"((v).z), "+v"((v).w))

// ---------------- dtype probe: 1=bf16 inputs, 0=fp32 inputs ----------------
__global__ void k_probe(const unsigned short* __restrict__ x, int* __restrict__ flag){
    __shared__ int cnt;
    if (threadIdx.x == 0) cnt = 0;
    __syncthreads();
    unsigned short u = x[2*threadIdx.x];
    int e = (u >> 7) & 0xFF;
    int ok = (u == 0) || (e >= 0x60 && e <= 0x85);
    unsigned long long m = __ballot(ok);
    if ((threadIdx.x & 63) == 0) atomicAdd(&cnt, __popcll(m));
    __syncthreads();
    if (threadIdx.x == 0) *flag = (cnt >= 128) ? 1 : 0;
}

// ---------------- x convert -> fp32 ----------------
__global__ void k_cvt(const void* __restrict__ src, float* __restrict__ dst,
                      int n, const int* __restrict__ flag){
    int i = blockIdx.x*256 + threadIdx.x;
    if (i >= n) return;
    if (*flag) dst[i] = bf2f(((const unsigned short*)src)[i]);
    else       dst[i] = ((const float*)src)[i];
}

// ---------------- fused param convert (10 tensors, one launch) ----------------
__global__ void k_cvtp(const void* s1, const void* s2, const void* s3, const void* s4,
                       const void* s5, const void* s6, const void* s7, const void* s8,
                       const void* s9, const void* s10,
                       float* d1, float* d2, float* d3, float* d4, float* d5,
                       float* d6, float* d7, float* d8, float* d9, float* d10,
                       const int* __restrict__ flag){
    int id = blockIdx.x*256 + threadIdx.x;
    const void* s; float* d; int off;
    if      (id <  8192){ s = s1;  d = d1;  off = id; }
    else if (id <  8320){ s = s2;  d = d2;  off = id - 8192; }
    else if (id <  8448){ s = s3;  d = d3;  off = id - 8320; }
    else if (id <  8576){ s = s4;  d = d4;  off = id - 8448; }
    else if (id < 16768){ s = s5;  d = d5;  off = id - 8576; }
    else if (id < 16832){ s = s6;  d = d6;  off = id - 16768; }
    else if (id < 16896){ s = s7;  d = d7;  off = id - 16832; }
    else if (id < 16960){ s = s8;  d = d8;  off = id - 16896; }
    else if (id < 21056){ s = s9;  d = d9;  off = id - 16960; }
    else if (id < 21120){ s = s10; d = d10; off = id - 21056; }
    else return;
    if (*flag) d[off] = bf2f(((const unsigned short*)s)[off]);
    else       d[off] = ((const float*)s)[off];
}

// ---------------- row norms: EXACT numpy fp32 pairwise semantics ----------------
__global__ void k_prep(const float* __restrict__ xf, float* __restrict__ nrmf){
    int i = blockIdx.x*64 + threadIdx.x;
    const float* xr = xf + i*D;
    float r[8];
    #pragma unroll
    for (int q = 0; q < 8; ++q) r[q] = __fmul_rn(xr[q], xr[q]);
    #pragma unroll
    for (int b = 8; b < 64; b += 8)
        #pragma unroll
        for (int q = 0; q < 8; ++q)
            r[q] = __fadd_rn(r[q], __fmul_rn(xr[b+q], xr[b+q]));
    float s = __fadd_rn(__fadd_rn(__fadd_rn(r[0],r[1]), __fadd_rn(r[2],r[3])),
                        __fadd_rn(__fadd_rn(r[4],r[5]), __fadd_rn(r[6],r[7])));
    nrmf[i] = __fsqrt_rn(s);
}

// =====================================================================
// Single-scan exact top-k with per-chunk top-8 certificate.
// ROUND-18 POST-MORTEM: "LDS roofline" was wrong — VGPR=56 < 64 (xi4
// partially demoted even in the LDS version) and VALUBusy 95% implies
// ~260 lane-ops/(q,j) vs ~75 algorithmic: the kernel is VALU/remat
// bound. Two untried levers here:
//  (1) __launch_bounds__(256,1): 512-VGPR budget + "1 wave/EU is OK"
//      removes the occupancy incentive to demote (LDS already caps the
//      CU at 4 blocks, so ~120 VGPR costs nothing).
//  (2) 2-j inner interleave (round-2-proven shape): one xi4 traversal
//      feeds two dots, halving whatever remat cost remains.
// List evolution stays EXACT: insert(j0) completes before j1's
// prefilter reads lv[TCH-1] (sequential j order preserved).
// CERTIFICATE (proven r15): elements not stored for chunk c rank below
// c's stored 8th; if no chunk's 8th outranks the provisional 16th, the
// 256-candidate union top-16 is exact. P(fire) ~ 3.7e-7/query; serial
// lane-0 fallback is a correctness net that ~never executes.
// Sim chain (bitwise-stable, operand-source independent):
//   a = fma-chain k=0..63; den = fadd(fmul(ni,nj),1e-8); s = fdiv(a,den).
// =====================================================================

__global__ __launch_bounds__(256, 1) void k_scan8(const float* __restrict__ xf,
                                                  const float* __restrict__ nrmf,
                                                  float* __restrict__ chV,
                                                  int* __restrict__ chI){
    __shared__ float sB[JTILE*64];   // 32 KB j-row tile
    __shared__ float sN[JTILE];

    int tid = threadIdx.x;
    int grp = blockIdx.x & 31;        // 32 query groups of 256
    int split = blockIdx.x >> 5;      // 32 chunks
    int i = grp*256 + tid;
    int jbase = split*JSPAN;

    const float4* xip = (const float4*)(xf + (size_t)i*D);
    float4 xi4[16];
    #pragma unroll
    for (int c = 0; c < 16; ++c) xi4[c] = xip[c];
    #pragma unroll
    for (int c = 0; c < 16; ++c) PIN4(xi4[c]);
    float ni = nrmf[i];

    float lv[TCH]; int li[TCH];
    #pragma unroll
    for (int r = 0; r < TCH; ++r){ lv[r] = -3.0e38f; li[r] = INT_MAX; }

    for (int t = 0; t < JSPAN/JTILE; ++t){
        int jt = jbase + t*JTILE;
        __syncthreads();   // previous tile fully consumed
        #pragma unroll
        for (int u = 0; u < (JTILE*16)/256; ++u){
            int idx = u*256 + tid;
            ((float4*)sB)[idx] = ((const float4*)xf)[(size_t)jt*16 + idx];
        }
        if (tid < JTILE) sN[tid] = nrmf[jt + tid];
        __syncthreads();

        for (int jj = 0; jj < JTILE; jj += 2){
            int j0 = jt + jj;
            int j1 = j0 + 1;
            const float4* B0 = (const float4*)(sB + jj*64);       // broadcast
            const float4* B1 = (const float4*)(sB + jj*64 + 64);
            float nj0 = sN[jj];
            float nj1 = sN[jj+1];
            float a0 = 0.0f, a1 = 0.0f;
            #pragma unroll
            for (int c = 0; c < 16; ++c){
                float4 b0 = B0[c], b1 = B1[c], xa = xi4[c];
                a0 = __fmaf_rn(b0.x, xa.x, a0);
                a0 = __fmaf_rn(b0.y, xa.y, a0);
                a0 = __fmaf_rn(b0.z, xa.z, a0);
                a0 = __fmaf_rn(b0.w, xa.w, a0);
                a1 = __fmaf_rn(b1.x, xa.x, a1);
                a1 = __fmaf_rn(b1.y, xa.y, a1);
                a1 = __fmaf_rn(b1.z, xa.z, a1);
                a1 = __fmaf_rn(b1.w, xa.w, a1);
            }
            // j0 first (sequential semantics), then j1 sees updated list
            float den0 = __fadd_rn(__fmul_rn(ni, nj0), 1e-8f);
            float thr0 = lv[TCH-1]*den0;
            if (j0 != i && a0 > __fmaf_rn(fabsf(thr0), -1e-6f, thr0)){
                float s0 = __fdiv_rn(a0, den0);
                if (s0 > lv[TCH-1]){
                    lv[TCH-1] = s0; li[TCH-1] = j0;
                    #pragma unroll
                    for (int r = TCH-1; r > 0; --r){
                        if (lv[r] > lv[r-1]){
                            float tv = lv[r]; lv[r] = lv[r-1]; lv[r-1] = tv;
                            int ti = li[r]; li[r] = li[r-1]; li[r-1] = ti;
                        }
                    }
                }
            }
            float den1 = __fadd_rn(__fmul_rn(ni, nj1), 1e-8f);
            float thr1 = lv[TCH-1]*den1;
            if (j1 != i && a1 > __fmaf_rn(fabsf(thr1), -1e-6f, thr1)){
                float s1 = __fdiv_rn(a1, den1);
                if (s1 > lv[TCH-1]){
                    lv[TCH-1] = s1; li[TCH-1] = j1;
                    #pragma unroll
                    for (int r = TCH-1; r > 0; --r){
                        if (lv[r] > lv[r-1]){
                            float tv = lv[r]; lv[r] = lv[r-1]; lv[r-1] = tv;
                            int ti = li[r]; li[r] = li[r-1]; li[r-1] = ti;
                        }
                    }
                }
            }
        }
    }
    // transposed layout: [(split*TCH+r)*N + i] — coalesced store
    #pragma unroll
    for (int r = 0; r < TCH; ++r){
        chV[(size_t)(split*TCH + r)*N + i] = lv[r];
        chI[(size_t)(split*TCH + r)*N + i] = li[r];
    }
}

// ---- wave-per-query exact top-16 of the 256-candidate union ----
// Also accumulates the weighted in-degree (fused former k_deg_scatter);
// degD must be pre-initialized to 2.0 (k_deg_init runs before k_scan8).
__global__ __launch_bounds__(256, 2) void k_sel16(const float* __restrict__ xf,
                                                  const float* __restrict__ nrmf,
                                                  const float* __restrict__ chV,
                                                  const int* __restrict__ chI,
                                                  int* __restrict__ topIdx,
                                                  float* __restrict__ ewArr,
                                                  double* __restrict__ degD){
    int q = (blockIdx.x*256 + threadIdx.x) >> 6;   // one wave per query
    int lane = threadIdx.x & 63;

    // load 4 slots per lane as order-preserving 64-bit keys
    unsigned long long okey[4], key[4];
    #pragma unroll
    for (int s = 0; s < 4; ++s){
        int slot = lane + 64*s;
        float v = chV[(size_t)slot*N + q];
        int  id = chI[(size_t)slot*N + q];
        unsigned int u = __float_as_uint(v);
        if ((u & 0x7FFFFFFFu) == 0u) u = 0u;              // -0 -> +0
        u = (u & 0x80000000u) ? ~u : (u | 0x80000000u);   // monotone float map
        unsigned long long kk = ((unsigned long long)u << 32)
                              | (unsigned long long)(unsigned int)(~(unsigned int)id);
        okey[s] = kk; key[s] = kk;
    }

    float wv[16]; int widx[16];
    unsigned long long k16 = 0ull;
    #pragma unroll
    for (int sel = 0; sel < KNB; ++sel){
        unsigned long long m = key[0] > key[1] ? key[0] : key[1];
        if (key[2] > m) m = key[2];
        if (key[3] > m) m = key[3];
        #pragma unroll
        for (int off = 32; off > 0; off >>= 1){
            unsigned long long o = __shfl_xor(m, off);
            if (o > m) m = o;
        }
        if      (key[0] == m) key[0] = 0ull;   // unique keys: exactly one owner
        else if (key[1] == m) key[1] = 0ull;
        else if (key[2] == m) key[2] = 0ull;
        else if (key[3] == m) key[3] = 0ull;
        unsigned int um = (unsigned int)(m >> 32);
        unsigned int ou = (um & 0x80000000u) ? (um & 0x7FFFFFFFu) : ~um;
        wv[sel]  = __uint_as_float(ou);
        widx[sel] = (int)~((unsigned int)m);
        k16 = m;
    }

    // certificate: does any chunk's stored 8th outrank the 16th selected?
    bool fl = false;
    #pragma unroll
    for (int s = 0; s < 4; ++s){
        int slot = lane + 64*s;
        if ((slot % TCH) == TCH-1 && okey[s] > k16) fl = true;
    }
    if (__ballot(fl) == 0ull){
        if (lane == 0){
            #pragma unroll
            for (int sel = 0; sel < KNB; ++sel){
                float w = (wv[sel] > 0.5f) ? wv[sel] : 0.0f;
                topIdx[q*KNB + sel] = widx[sel];
                ewArr [q*KNB + sel] = w;
                if (w > 0.0f) atomicAdd(&degD[widx[sel]], (double)w);
            }
        }
        return;
    }
    if (lane != 0) return;

    // ---- serial exact fallback (round-11 code; P(reach) ~ 3e-7/query) ----
    float lv[16]; int li[16];
    #pragma unroll
    for (int r = 0; r < 16; ++r){ lv[r] = -3.0e38f; li[r] = INT_MAX; }
    unsigned int flags = 0;
    for (int c = 0; c < NSPL; ++c){
        float v8 = chV[(size_t)(c*TCH + TCH-1)*N + q];
        int  i8 = chI[(size_t)(c*TCH + TCH-1)*N + q];
        if (v8 > wv[15] || (v8 == wv[15] && i8 < widx[15])) flags |= (1u << c);
    }
    const float4* xq4 = (const float4*)(xf + (size_t)q*D);
    float4 xq[16];
    #pragma unroll
    for (int c = 0; c < 16; ++c) xq[c] = xq4[c];
    float ni = nrmf[q];
    for (int c = 0; c < NSPL; ++c){
        if ((flags >> c) & 1u){
            for (int j = c*JSPAN; j < c*JSPAN + JSPAN; ++j){
                if (j == q) continue;
                const float4* b4 = (const float4*)(xf + (size_t)j*D);
                float a = 0.0f;
                #pragma unroll
                for (int k = 0; k < 16; ++k){
                    float4 b = b4[k]; float4 xa = xq[k];
                    a = __fmaf_rn(b.x, xa.x, a);
                    a = __fmaf_rn(b.y, xa.y, a);
                    a = __fmaf_rn(b.z, xa.z, a);
                    a = __fmaf_rn(b.w, xa.w, a);
                }
                float den = __fadd_rn(__fmul_rn(ni, nrmf[j]), 1e-8f);
                float s0 = __fdiv_rn(a, den);
                if (s0 > lv[15] || (s0 == lv[15] && j < li[15])){
                    lv[15] = s0; li[15] = j;
                    #pragma unroll
                    for (int k = 15; k > 0; --k){
                        if (lv[k] > lv[k-1] || (lv[k] == lv[k-1] && li[k] < li[k-1])){
                            float tv = lv[k]; lv[k] = lv[k-1]; lv[k-1] = tv;
                            int ti = li[k]; li[k] = li[k-1]; li[k-1] = ti;
                        }
                    }
                }
            }
        } else {
            #pragma unroll
            for (int r = 0; r < TCH; ++r){
                float v = chV[(size_t)(c*TCH + r)*N + q];
                int  id = chI[(size_t)(c*TCH + r)*N + q];
                if (v > lv[15] || (v == lv[15] && id < li[15])){
                    lv[15] = v; li[15] = id;
                    #pragma unroll
                    for (int k = 15; k > 0; --k){
                        if (lv[k] > lv[k-1] || (lv[k] == lv[k-1] && li[k] < li[k-1])){
                            float tv = lv[k]; lv[k] = lv[k-1]; lv[k-1] = tv;
                            int ti = li[k]; li[k] = li[k-1]; li[k-1] = ti;
                        }
                    }
                }
            }
        }
    }
    #pragma unroll
    for (int sel = 0; sel < KNB; ++sel){
        float w = (lv[sel] > 0.5f) ? lv[sel] : 0.0f;
        topIdx[q*KNB + sel] = li[sel];
        ewArr [q*KNB + sel] = w;
        if (w > 0.0f) atomicAdd(&degD[li[sel]], (double)w);
    }
}

// ---------------- degree / dinv ----------------
__global__ void k_deg_init(double* __restrict__ degD){
    int j = blockIdx.x*blockDim.x + threadIdx.x;
    if (j < N) degD[j] = 2.0;
}
__global__ void k_dinv(const double* __restrict__ degD, float* __restrict__ dinv){
    int j = blockIdx.x*blockDim.x + threadIdx.x;
    if (j < N) dinv[j] = (float)(1.0 / sqrt(degD[j]));
}

// ---------------- dense matmuls (fused agg self-loop init) ----------------
__global__ void k_gemm1(const float* __restrict__ xf, const float* __restrict__ W1,
                        const float* __restrict__ dinv,
                        float* __restrict__ h1, float* __restrict__ agg){
    int id = blockIdx.x*256 + threadIdx.x;
    int i = id >> 7; int f = id & (H-1);
    const float* xr = xf + i*D;
    float acc = 0.f;
    #pragma unroll
    for (int k = 0; k < D; ++k) acc += xr[k] * W1[k*H + f];
    h1[id] = acc;
    float dj = dinv[i];
    agg[id] = 2.f * dj * dj * acc;
}
__global__ void k_gemm2(const float* __restrict__ z1, const float* __restrict__ W2,
                        const float* __restrict__ dinv,
                        float* __restrict__ h2, float* __restrict__ agg){
    int id = blockIdx.x*256 + threadIdx.x;
    int i = id >> 6; int f = id & (O-1);
    const float* zr = z1 + i*H;
    float acc = 0.f;
    #pragma unroll
    for (int k = 0; k < H; ++k) acc += zr[k] * W2[k*O + f];
    h2[id] = acc;
    float dj = dinv[i];
    agg[id] = 2.f * dj * dj * acc;
}

// ---------------- GCN aggregation ----------------
// Grid-stride, WAVE-per-edge (round-16-proven: saved ~34us vs 131072
// one-edge workgroups). w==0 exit wave-uniform; reads/atomics coalesced.
template<int F>
__global__ __launch_bounds__(256) void k_agg_scat(const int* __restrict__ topIdx,
                                                  const float* __restrict__ ewArr,
                                                  const float* __restrict__ dinv,
                                                  const float* __restrict__ h,
                                                  float* __restrict__ agg){
    int wid = threadIdx.x >> 6;
    int lane = threadIdx.x & 63;
    for (int e = blockIdx.x*4 + wid; e < NE; e += gridDim.x*4){
        float w = ewArr[e];
        if (w == 0.f) continue;
        int s = e >> 4;
        int dn = topIdx[e];
        float c = dinv[s] * w * dinv[dn];
        #pragma unroll
        for (int p = 0; p < F/64; ++p){
            int f = lane + 64*p;
            atomicAdd(&agg[dn*F + f], c * h[s*F + f]);
        }
    }
}

// ---------------- bias + relu + layernorm ----------------
__global__ void k_post128(const float* __restrict__ agg, const float* __restrict__ b,
                          const float* __restrict__ g, const float* __restrict__ be,
                          float* __restrict__ z){
    __shared__ double s2[2];
    __shared__ double s3[2];
    int i = blockIdx.x; int f = threadIdx.x;
    float v = agg[i*H + f] + b[f];
    v = v > 0.f ? v : 0.f;
    int wid = f >> 6;
    double d = (double)v;
    for (int off = 32; off > 0; off >>= 1) d += __shfl_xor(d, off);
    if ((f & 63) == 0) s2[wid] = d;
    __syncthreads();
    double mu = (s2[0] + s2[1]) * (1.0/128.0);
    double dv = (double)v - mu;
    double qq = dv * dv;
    for (int off = 32; off > 0; off >>= 1) qq += __shfl_xor(qq, off);
    if ((f & 63) == 0) s3[wid] = qq;
    __syncthreads();
    double var = (s3[0] + s3[1]) * (1.0/128.0);
    double rs = 1.0 / sqrt(var + 1e-5);
    z[i*H + f] = (float)(dv * rs * (double)g[f] + (double)be[f]);
}
__global__ void k_post64(const float* __restrict__ agg, const float* __restrict__ b,
                         const float* __restrict__ g, const float* __restrict__ be,
                         float* __restrict__ z){
    int i = blockIdx.x; int f = threadIdx.x;
    float v = agg[i*O + f] + b[f];
    v = v > 0.f ? v : 0.f;
    double d = (double)v;
    for (int off = 32; off > 0; off >>= 1) d += __shfl_xor(d, off);
    double mu = d * (1.0/64.0);
    double dv = (double)v - mu;
    double qq = dv * dv;
    for (int off = 32; off > 0; off >>= 1) qq += __shfl_xor(qq, off);
    double var = qq * (1.0/64.0);
    double rs = 1.0 / sqrt(var + 1e-5);
    z[i*O + f] = (float)(dv * rs * (double)g[f] + (double)be[f]);
}

// ---------------- fused projection + output store + edges ----------------
__global__ void k_out(const float* __restrict__ z2, const float* __restrict__ Wp,
                      const float* __restrict__ bp, const int* __restrict__ topIdx,
                      const float* __restrict__ ewArr, void* __restrict__ outp,
                      const int* __restrict__ flag){
    int id = blockIdx.x*256 + threadIdx.x;
    if (id < OUT0){
        int i = id >> 6; int f = id & (D-1);
        const float* zr = z2 + i*O;
        float acc = bp[f];
        #pragma unroll
        for (int k = 0; k < O; ++k) acc += zr[k] * Wp[k*D + f];
        if (*flag) ((unsigned short*)outp)[id] = f2bf(acc);
        else       ((float*)outp)[id] = acc;
        return;
    }
    int e = id - OUT0;
    if (e >= ETOT) return;
    int s, dn; float w;
    if (e < NE){ s = e >> 4; dn = topIdx[e]; w = ewArr[e]; }
    else       { s = e - NE; dn = s;        w = 1.0f; }
    if (*flag){
        unsigned short* o = (unsigned short*)outp;
        o[OUT0 + e]          = f2bf((float)s);
        o[OUT0 + ETOT + e]   = f2bf((float)dn);
        o[OUT0 + 2*ETOT + e] = f2bf(w);
    } else {
        float* o = (float*)outp;
        o[OUT0 + e]          = (float)s;
        o[OUT0 + ETOT + e]   = (float)dn;
        o[OUT0 + 2*ETOT + e] = w;
    }
}

extern "C" void kernel_launch(void* const* d_in, const int* in_sizes, int n_in,
                              void* d_out, int out_size, void* d_ws, size_t ws_size,
                              hipStream_t stream){
    char* ws = (char*)d_ws;
    int*    flag   = (int*)   (ws + 0);
    float*  w1f    = (float*) (ws + 4096);
    float*  b1f    = (float*) (ws + 36864);
    float*  g1f    = (float*) (ws + 37376);
    float*  be1f   = (float*) (ws + 37888);
    float*  w2f    = (float*) (ws + 38400);
    float*  b2f    = (float*) (ws + 71168);
    float*  g2f    = (float*) (ws + 71424);
    float*  be2f   = (float*) (ws + 71680);
    float*  wpf    = (float*) (ws + 71936);
    float*  bpf    = (float*) (ws + 88320);
    float*  xf     = (float*) (ws + 98304);      // 2 MB          -> 2195456
    float*  nrmf   = (float*) (ws + 2195456);    // 32 KB         -> 2228224
    int*    topIdx = (int*)   (ws + 2260992);    // 512 KB        -> 2785280
    float*  ewArr  = (float*) (ws + 2785280);    // 512 KB        -> 3309568
    double* degD   = (double*)(ws + 3309568);    // 64 KB         -> 3375104
    float*  dinv   = (float*) (ws + 3375104);    // 32 KB         -> 3407872
    float*  h1     = (float*) (ws + 3407872);    // 4 MB          -> 7602176
    float*  agg1   = (float*) (ws + 7602176);    // 4 MB          -> 11796480
    float*  z1     = (float*) (ws + 11796480);   // 4 MB          -> 15990784
    float*  h2     = h1;
    float*  agg2   = agg1;
    float*  z2     = z1;

    // topk scratch overlaps h1/agg1/z1 (all dead until k_gemm1, which
    // launches after k_sel16): chV 8.39 MB @3407872, chI 8.39 MB
    // @11796480, end 20185088 — within ws (round 3 used ~37 MB here).
    float* chV = (float*)(ws + 3407872);
    int*   chI = (int*)  (ws + 11796480);

    k_probe<<<1, 256, 0, stream>>>((const unsigned short*)d_in[0], flag);
    k_cvt<<<(N*D+255)/256, 256, 0, stream>>>(d_in[0], xf,  N*D, flag);
    k_cvtp<<<(21120+255)/256, 256, 0, stream>>>(
        d_in[1], d_in[2], d_in[3], d_in[4], d_in[5],
        d_in[6], d_in[7], d_in[8], d_in[9], d_in[10],
        w1f, b1f, g1f, be1f, w2f, b2f, g2f, be2f, wpf, bpf, flag);

    k_prep<<<N/64, 64, 0, stream>>>(xf, nrmf);
    k_deg_init<<<N/256, 256, 0, stream>>>(degD);
    k_scan8<<<32*NSPL, 256, 0, stream>>>(xf, nrmf, chV, chI);
    k_sel16<<<(N*64)/256, 256, 0, stream>>>(xf, nrmf, chV, chI, topIdx, ewArr, degD);
    k_dinv<<<N/256, 256, 0, stream>>>(degD, dinv);

    k_gemm1<<<(N*H)/256, 256, 0, stream>>>(xf, w1f, dinv, h1, agg1);
    k_agg_scat<H><<<4096, 256, 0, stream>>>(topIdx, ewArr, dinv, h1, agg1);
    k_post128<<<N, H, 0, stream>>>(agg1, b1f, g1f, be1f, z1);

    k_gemm2<<<(N*O)/256, 256, 0, stream>>>(z1, w2f, dinv, h2, agg2);
    k_agg_scat<O><<<4096, 256, 0, stream>>>(topIdx, ewArr, dinv, h2, agg2);
    k_post64<<<N, O, 0, stream>>>(agg2, b2f, g2f, be2f, z2);

    k_out<<<(OUT0+ETOT+255)/256, 256, 0, stream>>>(z2, wpf, bpf, topIdx, ewArr,
                                                   d_out, flag);
}

// Round 20
// 399.047 us; speedup vs baseline: 1.1573x; 1.1573x over previous
//
#include <hip/hip_runtime.h>
#include <cstdint>
#include <climits>

#define N 8192
#define D 64
#define H 128
#define O 64
#define KNB 16
#define NE (N*KNB)        // 131072
#define ETOT (NE + N)     // 139264
#define OUT0 (N*D)        // 524288
#define NSPL 32           // j-splits (chunks)
#define JSPAN 256         // j's per chunk (N/NSPL)
#define JTILE 128         // j-rows staged in LDS per tile (32 KB)
#define TCH 8             // stored top-T per chunk (certificate depth)

__device__ __forceinline__ float bf2f(unsigned short u){
    union { unsigned int u; float f; } v; v.u = ((unsigned int)u) << 16; return v.f;
}
__device__ __forceinline__ unsigned short f2bf(float f){
    union { float f; unsigned int u; } v; v.f = f;
    unsigned int r = v.u + 0x7FFFu + ((v.u >> 16) & 1u);   // RNE
    return (unsigned short)(r >> 16);
}

#define PIN4(v) asm volatile("" : "+v"((v).x), "+v"((v).y), "+v"((v).z), "+v"((v).w))

// ---------------- dtype probe: 1=bf16 inputs, 0=fp32 inputs ----------------
__global__ void k_probe(const unsigned short* __restrict__ x, int* __restrict__ flag){
    __shared__ int cnt;
    if (threadIdx.x == 0) cnt = 0;
    __syncthreads();
    unsigned short u = x[2*threadIdx.x];
    int e = (u >> 7) & 0xFF;
    int ok = (u == 0) || (e >= 0x60 && e <= 0x85);
    unsigned long long m = __ballot(ok);
    if ((threadIdx.x & 63) == 0) atomicAdd(&cnt, __popcll(m));
    __syncthreads();
    if (threadIdx.x == 0) *flag = (cnt >= 128) ? 1 : 0;
}

// ---------------- x convert -> fp32 ----------------
__global__ void k_cvt(const void* __restrict__ src, float* __restrict__ dst,
                      int n, const int* __restrict__ flag){
    int i = blockIdx.x*256 + threadIdx.x;
    if (i >= n) return;
    if (*flag) dst[i] = bf2f(((const unsigned short*)src)[i]);
    else       dst[i] = ((const float*)src)[i];
}

// ---------------- fused param convert (10 tensors, one launch) ----------------
__global__ void k_cvtp(const void* s1, const void* s2, const void* s3, const void* s4,
                       const void* s5, const void* s6, const void* s7, const void* s8,
                       const void* s9, const void* s10,
                       float* d1, float* d2, float* d3, float* d4, float* d5,
                       float* d6, float* d7, float* d8, float* d9, float* d10,
                       const int* __restrict__ flag){
    int id = blockIdx.x*256 + threadIdx.x;
    const void* s; float* d; int off;
    if      (id <  8192){ s = s1;  d = d1;  off = id; }
    else if (id <  8320){ s = s2;  d = d2;  off = id - 8192; }
    else if (id <  8448){ s = s3;  d = d3;  off = id - 8320; }
    else if (id <  8576){ s = s4;  d = d4;  off = id - 8448; }
    else if (id < 16768){ s = s5;  d = d5;  off = id - 8576; }
    else if (id < 16832){ s = s6;  d = d6;  off = id - 16768; }
    else if (id < 16896){ s = s7;  d = d7;  off = id - 16832; }
    else if (id < 16960){ s = s8;  d = d8;  off = id - 16896; }
    else if (id < 21056){ s = s9;  d = d9;  off = id - 16960; }
    else if (id < 21120){ s = s10; d = d10; off = id - 21056; }
    else return;
    if (*flag) d[off] = bf2f(((const unsigned short*)s)[off]);
    else       d[off] = ((const float*)s)[off];
}

// ---------------- row norms (+ fused degD init) ----------------
__global__ void k_prep(const float* __restrict__ xf, float* __restrict__ nrmf,
                       double* __restrict__ degD){
    int i = blockIdx.x*64 + threadIdx.x;
    degD[i] = 2.0;                                  // fused former k_deg_init
    const float* xr = xf + i*D;
    float r[8];
    #pragma unroll
    for (int q = 0; q < 8; ++q) r[q] = __fmul_rn(xr[q], xr[q]);
    #pragma unroll
    for (int b = 8; b < 64; b += 8)
        #pragma unroll
        for (int q = 0; q < 8; ++q)
            r[q] = __fadd_rn(r[q], __fmul_rn(xr[b+q], xr[b+q]));
    float s = __fadd_rn(__fadd_rn(__fadd_rn(r[0],r[1]), __fadd_rn(r[2],r[3])),
                        __fadd_rn(__fadd_rn(r[4],r[5]), __fadd_rn(r[6],r[7])));
    nrmf[i] = __fsqrt_rn(s);
}

// =====================================================================
// Single-scan exact top-k with per-chunk top-8 certificate.
// k_scan8: round-15/17/18-proven configuration — LDS-broadcast j-rows,
// (256,2), single-j inner loop, 225-230us. ROUND-19 POST-MORTEM closed
// the last levers: (256,1) achieved partial residency (VGPR 96) but
// halved occupancy (40%->22%) for a net LOSS (291us); 2-j interleave
// didn't compensate. The allocator's occupancy/residency trade-off is
// pareto-flat ~230us across every reachable point (40/56/96 VGPR all
// measured); this config is the measured optimum.
// CERTIFICATE (proven r15): elements not stored for chunk c rank below
// c's stored 8th; if no chunk's 8th outranks the provisional 16th, the
// 256-candidate union top-16 is exact. P(fire) ~ 3.7e-7/query; serial
// lane-0 fallback is a correctness net that ~never executes.
// Sim chain (bitwise-stable, operand-source independent):
//   a = fma-chain k=0..63; den = fadd(fmul(ni,nj),1e-8); s = fdiv(a,den).
// =====================================================================

__global__ __launch_bounds__(256, 2) void k_scan8(const float* __restrict__ xf,
                                                  const float* __restrict__ nrmf,
                                                  float* __restrict__ chV,
                                                  int* __restrict__ chI){
    __shared__ float sB[JTILE*64];   // 32 KB j-row tile
    __shared__ float sN[JTILE];

    int tid = threadIdx.x;
    int grp = blockIdx.x & 31;        // 32 query groups of 256
    int split = blockIdx.x >> 5;      // 32 chunks
    int i = grp*256 + tid;
    int jbase = split*JSPAN;

    const float4* xip = (const float4*)(xf + (size_t)i*D);
    float4 xi4[16];
    #pragma unroll
    for (int c = 0; c < 16; ++c) xi4[c] = xip[c];
    #pragma unroll
    for (int c = 0; c < 16; ++c) PIN4(xi4[c]);
    float ni = nrmf[i];

    float lv[TCH]; int li[TCH];
    #pragma unroll
    for (int r = 0; r < TCH; ++r){ lv[r] = -3.0e38f; li[r] = INT_MAX; }

    for (int t = 0; t < JSPAN/JTILE; ++t){
        int jt = jbase + t*JTILE;
        __syncthreads();   // previous tile fully consumed
        #pragma unroll
        for (int u = 0; u < (JTILE*16)/256; ++u){
            int idx = u*256 + tid;
            ((float4*)sB)[idx] = ((const float4*)xf)[(size_t)jt*16 + idx];
        }
        if (tid < JTILE) sN[tid] = nrmf[jt + tid];
        __syncthreads();

        for (int jj = 0; jj < JTILE; ++jj){
            int j = jt + jj;
            const float4* B4 = (const float4*)(sB + jj*64);   // uniform -> broadcast
            float nj = sN[jj];
            float a = 0.0f;
            #pragma unroll
            for (int c = 0; c < 16; ++c){
                float4 b = B4[c]; float4 xa = xi4[c];
                a = __fmaf_rn(b.x, xa.x, a);
                a = __fmaf_rn(b.y, xa.y, a);
                a = __fmaf_rn(b.z, xa.z, a);
                a = __fmaf_rn(b.w, xa.w, a);
            }
            float den = __fadd_rn(__fmul_rn(ni, nj), 1e-8f);
            float thr = lv[TCH-1]*den;
            // conservative prefilter (margin >> fdiv rounding), exact recheck
            if (j != i && a > __fmaf_rn(fabsf(thr), -1e-6f, thr)){
                float s0 = __fdiv_rn(a, den);
                if (s0 > lv[TCH-1]){   // strict >: ties keep earlier idx (idx-asc rank)
                    lv[TCH-1] = s0; li[TCH-1] = j;
                    #pragma unroll
                    for (int r = TCH-1; r > 0; --r){
                        if (lv[r] > lv[r-1]){
                            float tv = lv[r]; lv[r] = lv[r-1]; lv[r-1] = tv;
                            int ti = li[r]; li[r] = li[r-1]; li[r-1] = ti;
                        }
                    }
                }
            }
        }
    }
    // transposed layout: [(split*TCH+r)*N + i] — coalesced store
    #pragma unroll
    for (int r = 0; r < TCH; ++r){
        chV[(size_t)(split*TCH + r)*N + i] = lv[r];
        chI[(size_t)(split*TCH + r)*N + i] = li[r];
    }
}

// ---- wave-per-query exact top-16 of the 256-candidate union ----
// Also accumulates the weighted in-degree (fused former k_deg_scatter);
// degD pre-initialized to 2.0 in k_prep.
__global__ __launch_bounds__(256, 2) void k_sel16(const float* __restrict__ xf,
                                                  const float* __restrict__ nrmf,
                                                  const float* __restrict__ chV,
                                                  const int* __restrict__ chI,
                                                  int* __restrict__ topIdx,
                                                  float* __restrict__ ewArr,
                                                  double* __restrict__ degD){
    int q = (blockIdx.x*256 + threadIdx.x) >> 6;   // one wave per query
    int lane = threadIdx.x & 63;

    // load 4 slots per lane as order-preserving 64-bit keys
    unsigned long long okey[4], key[4];
    #pragma unroll
    for (int s = 0; s < 4; ++s){
        int slot = lane + 64*s;
        float v = chV[(size_t)slot*N + q];
        int  id = chI[(size_t)slot*N + q];
        unsigned int u = __float_as_uint(v);
        if ((u & 0x7FFFFFFFu) == 0u) u = 0u;              // -0 -> +0
        u = (u & 0x80000000u) ? ~u : (u | 0x80000000u);   // monotone float map
        unsigned long long kk = ((unsigned long long)u << 32)
                              | (unsigned long long)(unsigned int)(~(unsigned int)id);
        okey[s] = kk; key[s] = kk;
    }

    float wv[16]; int widx[16];
    unsigned long long k16 = 0ull;
    #pragma unroll
    for (int sel = 0; sel < KNB; ++sel){
        unsigned long long m = key[0] > key[1] ? key[0] : key[1];
        if (key[2] > m) m = key[2];
        if (key[3] > m) m = key[3];
        #pragma unroll
        for (int off = 32; off > 0; off >>= 1){
            unsigned long long o = __shfl_xor(m, off);
            if (o > m) m = o;
        }
        if      (key[0] == m) key[0] = 0ull;   // unique keys: exactly one owner
        else if (key[1] == m) key[1] = 0ull;
        else if (key[2] == m) key[2] = 0ull;
        else if (key[3] == m) key[3] = 0ull;
        unsigned int um = (unsigned int)(m >> 32);
        unsigned int ou = (um & 0x80000000u) ? (um & 0x7FFFFFFFu) : ~um;
        wv[sel]  = __uint_as_float(ou);
        widx[sel] = (int)~((unsigned int)m);
        k16 = m;
    }

    // certificate: does any chunk's stored 8th outrank the 16th selected?
    bool fl = false;
    #pragma unroll
    for (int s = 0; s < 4; ++s){
        int slot = lane + 64*s;
        if ((slot % TCH) == TCH-1 && okey[s] > k16) fl = true;
    }
    if (__ballot(fl) == 0ull){
        if (lane == 0){
            #pragma unroll
            for (int sel = 0; sel < KNB; ++sel){
                float w = (wv[sel] > 0.5f) ? wv[sel] : 0.0f;
                topIdx[q*KNB + sel] = widx[sel];
                ewArr [q*KNB + sel] = w;
                if (w > 0.0f) atomicAdd(&degD[widx[sel]], (double)w);
            }
        }
        return;
    }
    if (lane != 0) return;

    // ---- serial exact fallback (round-11 code; P(reach) ~ 3e-7/query) ----
    float lv[16]; int li[16];
    #pragma unroll
    for (int r = 0; r < 16; ++r){ lv[r] = -3.0e38f; li[r] = INT_MAX; }
    unsigned int flags = 0;
    for (int c = 0; c < NSPL; ++c){
        float v8 = chV[(size_t)(c*TCH + TCH-1)*N + q];
        int  i8 = chI[(size_t)(c*TCH + TCH-1)*N + q];
        if (v8 > wv[15] || (v8 == wv[15] && i8 < widx[15])) flags |= (1u << c);
    }
    const float4* xq4 = (const float4*)(xf + (size_t)q*D);
    float4 xq[16];
    #pragma unroll
    for (int c = 0; c < 16; ++c) xq[c] = xq4[c];
    float ni = nrmf[q];
    for (int c = 0; c < NSPL; ++c){
        if ((flags >> c) & 1u){
            for (int j = c*JSPAN; j < c*JSPAN + JSPAN; ++j){
                if (j == q) continue;
                const float4* b4 = (const float4*)(xf + (size_t)j*D);
                float a = 0.0f;
                #pragma unroll
                for (int k = 0; k < 16; ++k){
                    float4 b = b4[k]; float4 xa = xq[k];
                    a = __fmaf_rn(b.x, xa.x, a);
                    a = __fmaf_rn(b.y, xa.y, a);
                    a = __fmaf_rn(b.z, xa.z, a);
                    a = __fmaf_rn(b.w, xa.w, a);
                }
                float den = __fadd_rn(__fmul_rn(ni, nrmf[j]), 1e-8f);
                float s0 = __fdiv_rn(a, den);
                if (s0 > lv[15] || (s0 == lv[15] && j < li[15])){
                    lv[15] = s0; li[15] = j;
                    #pragma unroll
                    for (int k = 15; k > 0; --k){
                        if (lv[k] > lv[k-1] || (lv[k] == lv[k-1] && li[k] < li[k-1])){
                            float tv = lv[k]; lv[k] = lv[k-1]; lv[k-1] = tv;
                            int ti = li[k]; li[k] = li[k-1]; li[k-1] = ti;
                        }
                    }
                }
            }
        } else {
            #pragma unroll
            for (int r = 0; r < TCH; ++r){
                float v = chV[(size_t)(c*TCH + r)*N + q];
                int  id = chI[(size_t)(c*TCH + r)*N + q];
                if (v > lv[15] || (v == lv[15] && id < li[15])){
                    lv[15] = v; li[15] = id;
                    #pragma unroll
                    for (int k = 15; k > 0; --k){
                        if (lv[k] > lv[k-1] || (lv[k] == lv[k-1] && li[k] < li[k-1])){
                            float tv = lv[k]; lv[k] = lv[k-1]; lv[k-1] = tv;
                            int ti = li[k]; li[k] = li[k-1]; li[k-1] = ti;
                        }
                    }
                }
            }
        }
    }
    #pragma unroll
    for (int sel = 0; sel < KNB; ++sel){
        float w = (lv[sel] > 0.5f) ? lv[sel] : 0.0f;
        topIdx[q*KNB + sel] = li[sel];
        ewArr [q*KNB + sel] = w;
        if (w > 0.0f) atomicAdd(&degD[li[sel]], (double)w);
    }
}

// ---------------- dinv ----------------
__global__ void k_dinv(const double* __restrict__ degD, float* __restrict__ dinv){
    int j = blockIdx.x*blockDim.x + threadIdx.x;
    if (j < N) dinv[j] = (float)(1.0 / sqrt(degD[j]));
}

// ---------------- dense matmuls (fused agg self-loop init) ----------------
__global__ void k_gemm1(const float* __restrict__ xf, const float* __restrict__ W1,
                        const float* __restrict__ dinv,
                        float* __restrict__ h1, float* __restrict__ agg){
    int id = blockIdx.x*256 + threadIdx.x;
    int i = id >> 7; int f = id & (H-1);
    const float* xr = xf + i*D;
    float acc = 0.f;
    #pragma unroll
    for (int k = 0; k < D; ++k) acc += xr[k] * W1[k*H + f];
    h1[id] = acc;
    float dj = dinv[i];
    agg[id] = 2.f * dj * dj * acc;
}
__global__ void k_gemm2(const float* __restrict__ z1, const float* __restrict__ W2,
                        const float* __restrict__ dinv,
                        float* __restrict__ h2, float* __restrict__ agg){
    int id = blockIdx.x*256 + threadIdx.x;
    int i = id >> 6; int f = id & (O-1);
    const float* zr = z1 + i*H;
    float acc = 0.f;
    #pragma unroll
    for (int k = 0; k < H; ++k) acc += zr[k] * W2[k*O + f];
    h2[id] = acc;
    float dj = dinv[i];
    agg[id] = 2.f * dj * dj * acc;
}

// ---------------- GCN aggregation ----------------
// Grid-stride, WAVE-per-edge (round-16-proven: saved ~34us vs 131072
// one-edge workgroups). w==0 exit wave-uniform; reads/atomics coalesced.
template<int F>
__global__ __launch_bounds__(256) void k_agg_scat(const int* __restrict__ topIdx,
                                                  const float* __restrict__ ewArr,
                                                  const float* __restrict__ dinv,
                                                  const float* __restrict__ h,
                                                  float* __restrict__ agg){
    int wid = threadIdx.x >> 6;
    int lane = threadIdx.x & 63;
    for (int e = blockIdx.x*4 + wid; e < NE; e += gridDim.x*4){
        float w = ewArr[e];
        if (w == 0.f) continue;
        int s = e >> 4;
        int dn = topIdx[e];
        float c = dinv[s] * w * dinv[dn];
        #pragma unroll
        for (int p = 0; p < F/64; ++p){
            int f = lane + 64*p;
            atomicAdd(&agg[dn*F + f], c * h[s*F + f]);
        }
    }
}

// ---------------- bias + relu + layernorm ----------------
__global__ void k_post128(const float* __restrict__ agg, const float* __restrict__ b,
                          const float* __restrict__ g, const float* __restrict__ be,
                          float* __restrict__ z){
    __shared__ double s2[2];
    __shared__ double s3[2];
    int i = blockIdx.x; int f = threadIdx.x;
    float v = agg[i*H + f] + b[f];
    v = v > 0.f ? v : 0.f;
    int wid = f >> 6;
    double d = (double)v;
    for (int off = 32; off > 0; off >>= 1) d += __shfl_xor(d, off);
    if ((f & 63) == 0) s2[wid] = d;
    __syncthreads();
    double mu = (s2[0] + s2[1]) * (1.0/128.0);
    double dv = (double)v - mu;
    double qq = dv * dv;
    for (int off = 32; off > 0; off >>= 1) qq += __shfl_xor(qq, off);
    if ((f & 63) == 0) s3[wid] = qq;
    __syncthreads();
    double var = (s3[0] + s3[1]) * (1.0/128.0);
    double rs = 1.0 / sqrt(var + 1e-5);
    z[i*H + f] = (float)(dv * rs * (double)g[f] + (double)be[f]);
}
__global__ void k_post64(const float* __restrict__ agg, const float* __restrict__ b,
                         const float* __restrict__ g, const float* __restrict__ be,
                         float* __restrict__ z){
    int i = blockIdx.x; int f = threadIdx.x;
    float v = agg[i*O + f] + b[f];
    v = v > 0.f ? v : 0.f;
    double d = (double)v;
    for (int off = 32; off > 0; off >>= 1) d += __shfl_xor(d, off);
    double mu = d * (1.0/64.0);
    double dv = (double)v - mu;
    double qq = dv * dv;
    for (int off = 32; off > 0; off >>= 1) qq += __shfl_xor(qq, off);
    double var = qq * (1.0/64.0);
    double rs = 1.0 / sqrt(var + 1e-5);
    z[i*O + f] = (float)(dv * rs * (double)g[f] + (double)be[f]);
}

// ---------------- fused projection + output store + edges ----------------
__global__ void k_out(const float* __restrict__ z2, const float* __restrict__ Wp,
                      const float* __restrict__ bp, const int* __restrict__ topIdx,
                      const float* __restrict__ ewArr, void* __restrict__ outp,
                      const int* __restrict__ flag){
    int id = blockIdx.x*256 + threadIdx.x;
    if (id < OUT0){
        int i = id >> 6; int f = id & (D-1);
        const float* zr = z2 + i*O;
        float acc = bp[f];
        #pragma unroll
        for (int k = 0; k < O; ++k) acc += zr[k] * Wp[k*D + f];
        if (*flag) ((unsigned short*)outp)[id] = f2bf(acc);
        else       ((float*)outp)[id] = acc;
        return;
    }
    int e = id - OUT0;
    if (e >= ETOT) return;
    int s, dn; float w;
    if (e < NE){ s = e >> 4; dn = topIdx[e]; w = ewArr[e]; }
    else       { s = e - NE; dn = s;        w = 1.0f; }
    if (*flag){
        unsigned short* o = (unsigned short*)outp;
        o[OUT0 + e]          = f2bf((float)s);
        o[OUT0 + ETOT + e]   = f2bf((float)dn);
        o[OUT0 + 2*ETOT + e] = f2bf(w);
    } else {
        float* o = (float*)outp;
        o[OUT0 + e]          = (float)s;
        o[OUT0 + ETOT + e]   = (float)dn;
        o[OUT0 + 2*ETOT + e] = w;
    }
}

extern "C" void kernel_launch(void* const* d_in, const int* in_sizes, int n_in,
                              void* d_out, int out_size, void* d_ws, size_t ws_size,
                              hipStream_t stream){
    char* ws = (char*)d_ws;
    int*    flag   = (int*)   (ws + 0);
    float*  w1f    = (float*) (ws + 4096);
    float*  b1f    = (float*) (ws + 36864);
    float*  g1f    = (float*) (ws + 37376);
    float*  be1f   = (float*) (ws + 37888);
    float*  w2f    = (float*) (ws + 38400);
    float*  b2f    = (float*) (ws + 71168);
    float*  g2f    = (float*) (ws + 71424);
    float*  be2f   = (float*) (ws + 71680);
    float*  wpf    = (float*) (ws + 71936);
    float*  bpf    = (float*) (ws + 88320);
    float*  xf     = (float*) (ws + 98304);      // 2 MB          -> 2195456
    float*  nrmf   = (float*) (ws + 2195456);    // 32 KB         -> 2228224
    int*    topIdx = (int*)   (ws + 2260992);    // 512 KB        -> 2785280
    float*  ewArr  = (float*) (ws + 2785280);    // 512 KB        -> 3309568
    double* degD   = (double*)(ws + 3309568);    // 64 KB         -> 3375104
    float*  dinv   = (float*) (ws + 3375104);    // 32 KB         -> 3407872
    float*  h1     = (float*) (ws + 3407872);    // 4 MB          -> 7602176
    float*  agg1   = (float*) (ws + 7602176);    // 4 MB          -> 11796480
    float*  z1     = (float*) (ws + 11796480);   // 4 MB          -> 15990784
    float*  h2     = h1;
    float*  agg2   = agg1;
    float*  z2     = z1;

    // topk scratch overlaps h1/agg1/z1 (all dead until k_gemm1, which
    // launches after k_sel16): chV 8.39 MB @3407872, chI 8.39 MB
    // @11796480, end 20185088 — within ws (round 3 used ~37 MB here).
    float* chV = (float*)(ws + 3407872);
    int*   chI = (int*)  (ws + 11796480);

    k_probe<<<1, 256, 0, stream>>>((const unsigned short*)d_in[0], flag);
    k_cvt<<<(N*D+255)/256, 256, 0, stream>>>(d_in[0], xf,  N*D, flag);
    k_cvtp<<<(21120+255)/256, 256, 0, stream>>>(
        d_in[1], d_in[2], d_in[3], d_in[4], d_in[5],
        d_in[6], d_in[7], d_in[8], d_in[9], d_in[10],
        w1f, b1f, g1f, be1f, w2f, b2f, g2f, be2f, wpf, bpf, flag);

    k_prep<<<N/64, 64, 0, stream>>>(xf, nrmf, degD);
    k_scan8<<<32*NSPL, 256, 0, stream>>>(xf, nrmf, chV, chI);
    k_sel16<<<(N*64)/256, 256, 0, stream>>>(xf, nrmf, chV, chI, topIdx, ewArr, degD);
    k_dinv<<<N/256, 256, 0, stream>>>(degD, dinv);

    k_gemm1<<<(N*H)/256, 256, 0, stream>>>(xf, w1f, dinv, h1, agg1);
    k_agg_scat<H><<<4096, 256, 0, stream>>>(topIdx, ewArr, dinv, h1, agg1);
    k_post128<<<N, H, 0, stream>>>(agg1, b1f, g1f, be1f, z1);

    k_gemm2<<<(N*O)/256, 256, 0, stream>>>(z1, w2f, dinv, h2, agg2);
    k_agg_scat<O><<<4096, 256, 0, stream>>>(topIdx, ewArr, dinv, h2, agg2);
    k_post64<<<N, O, 0, stream>>>(agg2, b2f, g2f, be2f, z2);

    k_out<<<(OUT0+ETOT+255)/256, 256, 0, stream>>>(z2, wpf, bpf, topIdx, ewArr,
                                                   d_out, flag);
}